// Round 6
// baseline (447.707 us; speedup 1.0000x reference)
//
#include <hip/hip_runtime.h>
#include <cstdint>
#include <cstddef>

// LLAConv2d: per-sample 1x1 conv == 32 independent GEMMs
//   out[b,o,p] = sum_i K[b,o,i] * x[b,i,p],  K[b] = sum_e alpha[b,e]*ke[e]
// B=32, Cin=Cout=64, P=160*160=25600, fp32.
// Floors: HBM ~50us (measured 317MB @6.4TB/s), fp32 VALU 43us pure FMA
// (no fp32 MFMA on CDNA4), ~50-60us with bookkeeping.
// Pipe model (validated R2-R7): FMA 2cy/inst/SIMD; ds_read_b128 ~12cy on the
// per-CU DS pipe (even broadcasts pay writeback); SMEM un-pipelinable for
// streams (SGPR budget: R6 stalled 250cy/ii); SMEM+DS share lgkmcnt and SMEM
// is OOO -> mixing forces drains (R4); naked compiler-scheduled global-x can
// collapse to zero loads in flight (R5, VGPR=36); hand-rolled asm vmcnt on
// REGISTER dests is unsafe (R7 NaN) -- LDS-dest ledgers or C-level rotation
// only. R6 proved a C-level depth-2 float4 rotation stays in flight.
// R8 = R7 geometry + R6 x-path:
//   k from LDS: 2 wave-uniform ds_read_b128 broadcasts per K-step
//     -> DS budget 16 waves * 24cy = 384 < 512cy CU window. No SMEM anywhere.
//   x from global: 2 dense coalesced float4 loads per thread per K-step
//     (two 1KB half-rows), explicit depth-2 rotation, compiler vmcnt.
//   8ch x 8px per thread = 64 FMA per (2 ds + 2 vmem) -> FMA-bound.

#define PIX 25600
#define CIN 64
#define COUT 64
#define BATCH 32
#define NEXP 8
#define TILE_PX 512
#define PTILES (PIX / TILE_PX)    // 50
#define GRID (BATCH * PTILES * 2) // 3200: 32 b x 50 px-tiles x 2 o-halves

__device__ __forceinline__ void load_lds16(const float* g, float* l) {
  // async global->LDS, 16B/lane; global addr per-lane, LDS dst uniform+lane*16
  __builtin_amdgcn_global_load_lds(
      (__attribute__((address_space(1))) void*)(g),
      (__attribute__((address_space(3))) void*)(l), 16, 0, 0);
}

// ---------------- Kernel A: mix kernels, store kt[b][i][o] ------------------
__global__ __launch_bounds__(256) void mix_kernel(
    const float* __restrict__ alpha, const float* __restrict__ ke,
    float* __restrict__ kt) {
  const int b = blockIdx.x >> 3;
  const int seg = blockIdx.x & 7;
  __shared__ float a[NEXP];
  if (threadIdx.x < NEXP) a[threadIdx.x] = alpha[b * NEXP + threadIdx.x];
  __syncthreads();
#pragma unroll
  for (int t = 0; t < 2; t++) {
    const int idx = seg * 512 + t * 256 + threadIdx.x; // idx = o*64 + i
    float s = 0.f;
#pragma unroll
    for (int e = 0; e < NEXP; e++) s += a[e] * ke[e * 4096 + idx];
    const int o = idx >> 6, i = idx & 63;
    kt[b * 4096 + i * 64 + o] = s; // [b][i][o]: rows of 64 out-chans
  }
}

// ---------------- Kernel B: LDS-k / rotated-global-x 1x1-conv GEMM ----------
// Block = 32ch (o-half) x 512px; wave w owns ch [8w,8w+8); lane owns px
// {P0+4l..+4} and {P0+256+4l..+4} (two dense 1KB half-rows -> perfect
// stride-16B coalescing per load instr).
// k: ks[ii][32] staged once (8KB via global_load_lds); per K-step two
//    ds_read_b128 at ONE wave-uniform address each -> broadcast, conflict-
//    free, in-order lgkmcnt (compiler-counted).
// x: per K-step 2 float4 global loads/thread; explicit depth-2 rotation
//    (xa<-xb<-xn, static slots) so >=2 K-rows of loads stay in flight (the
//    R6-proven pattern); 4 waves/block read identical bytes -> L1 hits.
// One __syncthreads total (k-stage drain). FMA order ascending ii -> exact.
__global__ __launch_bounds__(256, 4) void conv_kernel(
    const float* __restrict__ x, const float* __restrict__ kt,
    float* __restrict__ out) {
  __shared__ float ks[CIN * 32]; // [ii][32 o-half], 8KB

  const int bid = blockIdx.x;
  const int b = bid / (PTILES * 2);
  const int rem = bid - b * (PTILES * 2);
  const int oh = rem & 1; // o-half; oh-pair blocks adjacent -> share x in L2/L3
  const int t = rem >> 1; // px tile
  const int P0 = t * TILE_PX;

  const int tid = threadIdx.x;
  const int wave = tid >> 6;
  const int lane = tid & 63;

  // Stage ks: 2048 floats = 8 instrs; wave w does j = 2w, 2w+1.
  // instr j covers linear elems [256j,256j+256): lane l -> e0 = 256j + 4l;
  // src row ii = e0>>5, col = e0&31 (16B inside one 32-col half-row, aligned).
  const float* kb = kt + b * 4096 + oh * 32;
#pragma unroll
  for (int jj = 0; jj < 2; jj++) {
    const int j = wave * 2 + jj;
    const int e0 = j * 256 + lane * 4;
    load_lds16(kb + (e0 >> 5) * 64 + (e0 & 31), &ks[j * 256]);
  }
  __syncthreads(); // only barrier in the kernel (drains the stage)

  // x pointers: two dense half-rows per K-row
  const float* xp = x + (size_t)b * CIN * PIX + P0 + lane * 4;

  float acc[8][8];
#pragma unroll
  for (int c = 0; c < 8; c++)
#pragma unroll
    for (int p = 0; p < 8; p++) acc[c][p] = 0.f;

  // depth-2 x prefetch rotation (static slots; R6-proven to stay in flight)
  float4 xa0 = *(const float4*)(xp);
  float4 xa1 = *(const float4*)(xp + 256);
  float4 xb0 = *(const float4*)(xp + PIX);
  float4 xb1 = *(const float4*)(xp + PIX + 256);

  const float* kw = ks + wave * 8; // wave's 8 channels within the 32-row

#pragma unroll 4
  for (int ii = 0; ii < CIN; ii++) {
    const int iin = (ii + 2 < CIN) ? (ii + 2) : (CIN - 1); // clamp: safe addr
    const float4 xn0 = *(const float4*)(xp + (size_t)iin * PIX);
    const float4 xn1 = *(const float4*)(xp + (size_t)iin * PIX + 256);

    // k: two wave-uniform broadcast ds_read_b128
    const float4 k0 = *(const float4*)(kw + ii * 32);
    const float4 k1 = *(const float4*)(kw + ii * 32 + 4);
    const float kc[8] = {k0.x, k0.y, k0.z, k0.w, k1.x, k1.y, k1.z, k1.w};
    const float xv[8] = {xa0.x, xa0.y, xa0.z, xa0.w,
                         xa1.x, xa1.y, xa1.z, xa1.w};
#pragma unroll
    for (int c = 0; c < 8; c++)
#pragma unroll
      for (int p = 0; p < 8; p++) acc[c][p] = fmaf(kc[c], xv[p], acc[c][p]);

    xa0 = xb0; xa1 = xb1;
    xb0 = xn0; xb1 = xn1;
  }

  // Epilogue: per channel two float4 stores (two dense 1KB half-rows).
  float* ob = out + ((size_t)(b * COUT + oh * 32 + wave * 8)) * PIX + P0 +
              lane * 4;
#pragma unroll
  for (int c = 0; c < 8; c++) {
    *(float4*)(ob + (size_t)c * PIX) =
        make_float4(acc[c][0], acc[c][1], acc[c][2], acc[c][3]);
    *(float4*)(ob + (size_t)c * PIX + 256) =
        make_float4(acc[c][4], acc[c][5], acc[c][6], acc[c][7]);
  }
}

extern "C" void kernel_launch(void* const* d_in, const int* in_sizes, int n_in,
                              void* d_out, int out_size, void* d_ws,
                              size_t ws_size, hipStream_t stream) {
  const float* x = (const float*)d_in[0];     // [32,64,160,160]
  const float* alpha = (const float*)d_in[1]; // [32,8]
  const float* ke = (const float*)d_in[2];    // [8,64,64,1,1]
  float* out = (float*)d_out;                 // [32,64,160,160]
  float* kt = (float*)d_ws;                   // 32*4096 floats = 512KB scratch

  mix_kernel<<<BATCH * 8, 256, 0, stream>>>(alpha, ke, kt);
  conv_kernel<<<GRID, 256, 0, stream>>>(x, kt, out);
}